// Round 13
// baseline (821.114 us; speedup 1.0000x reference)
//
#include <hip/hip_runtime.h>

// Joiner fused one-pass: out[b,t,u,v] = relu(src[b,t,:]+tgt[b,u,:]) . W[v,:] + b[v]
// B=4 T=256 U=128 D=512 V=1024. M = B*T*U = 131072, K=512, N=1024.
// Each block owns one bt (=b*T+t): its 128 act rows = src[bt,:] + tgt[b,u,:], u=0..127.
// act slab (128x512 bf16 = 128 KiB) generated ONCE into LDS (XOR-swizzled);
// B-chunks (128 cols x 64 k, 16 KiB) double-buffered via global_load_lds (linear);
// sweep nt=0..7, k-steps 0..7, per-nt epilogue writes 128x128 fp32 + bias.
// HBM: ~537 MB out write + ~10 MB reads (src/tgt/Wb all L2/L3-resident).

typedef __attribute__((ext_vector_type(4))) float f32x4;
typedef __attribute__((ext_vector_type(8))) __bf16 bf16x8;
typedef __attribute__((ext_vector_type(8))) unsigned short u16x8;

#define KDIM 512
#define VDIM 1024
#define BK 64
#define OUT_MAIN 134217728ull   // 131072 * 1024

__device__ __forceinline__ unsigned short f2bf(float f) {
    unsigned u = __float_as_uint(f);
    unsigned r = 0x7fffu + ((u >> 16) & 1u);   // round-to-nearest-even
    return (unsigned short)((u + r) >> 16);
}

// ---- pass 1: Wb = bf16(W) into ws, lengths -> out tail as floats ----
__global__ __launch_bounds__(256) void prep_w(const float* __restrict__ W,
                                              unsigned short* __restrict__ Wb,
                                              const int* __restrict__ slen,
                                              const int* __restrict__ tlen,
                                              float* __restrict__ tail) {
    int idx = blockIdx.x * 256 + threadIdx.x;   // 0..65535
    const float* wp = W + ((size_t)idx << 3);
    f32x4 w0 = *(const f32x4*)wp;
    f32x4 w1 = *(const f32x4*)(wp + 4);
    u16x8 r;
#pragma unroll
    for (int j = 0; j < 4; j++) { r[j] = f2bf(w0[j]); r[j + 4] = f2bf(w1[j]); }
    *(u16x8*)(Wb + ((size_t)idx << 3)) = r;
    if (idx < 4)      tail[idx] = (float)slen[idx];
    else if (idx < 8) tail[idx] = (float)tlen[idx - 4];
}

// ---- pass 2: fused act-gen + GEMM ----
// 512 threads = 8 waves (4M x 2N). Per wave: 32 rows x 64 cols, acc[2][4] f32x4.
__global__ __launch_bounds__(512, 1) void joiner_fused(
    const float* __restrict__ src, const float* __restrict__ tgt,
    const unsigned short* __restrict__ Wb, const float* __restrict__ bias,
    float* __restrict__ out)
{
    __shared__ __align__(16) unsigned short As[128 * KDIM];   // 128 KiB, swizzled
    __shared__ __align__(16) unsigned short Bs[2][128 * BK];  // 32 KiB, linear

    const int tid = threadIdx.x;
    const int bt  = blockIdx.x;          // 0..1023
    const int b   = bt >> 8;             // T = 256

    // B staging ids: thread t stages 2x16B; dest elem = t*8 (+4096), linear in t.
    const int scol = tid >> 3;           // 0..63
    const int skb  = (tid & 7) * 8;      // k offset within chunk

    // -- prefetch B chunk 0 (nt=0,k0=0) into Bs[0], overlaps A-gen VALU --
    __builtin_amdgcn_global_load_lds(
        (const __attribute__((address_space(1))) void*)(Wb + (size_t)scol * KDIM + skb),
        (__attribute__((address_space(3))) void*)(&Bs[0][scol * BK + skb]), 16, 0, 0);
    __builtin_amdgcn_global_load_lds(
        (const __attribute__((address_space(1))) void*)(Wb + (size_t)(64 + scol) * KDIM + skb),
        (__attribute__((address_space(3))) void*)(&Bs[0][(64 + scol) * BK + skb]), 16, 0, 0);

    // -- A-gen: As[r][k] = bf16(relu(src[bt][k] + tgt[b*128+r][k])), swizzled --
    // swizzle: phys_elem = r*512 + (k ^ ((r&7)<<3))  (flips k bits 3..5; 16B-preserving)
    {
        const int r = tid >> 2;              // 0..127
        const int q = tid & 3;               // k quarter [q*128, q*128+128)
        const float* sp = src + (size_t)bt * KDIM + q * 128;
        const float* tp = tgt + (size_t)(b * 128 + r) * KDIM + q * 128;
        const int rx = (r & 7) << 3;
#pragma unroll
        for (int ch = 0; ch < 16; ++ch) {
            f32x4 s0 = *(const f32x4*)(sp + ch * 8);
            f32x4 s1 = *(const f32x4*)(sp + ch * 8 + 4);
            f32x4 t0 = *(const f32x4*)(tp + ch * 8);
            f32x4 t1 = *(const f32x4*)(tp + ch * 8 + 4);
            u16x8 v;
#pragma unroll
            for (int j = 0; j < 4; j++) {
                float a = s0[j] + t0[j]; a = a > 0.f ? a : 0.f;
                float c = s1[j] + t1[j]; c = c > 0.f ? c : 0.f;
                v[j]     = f2bf(a);
                v[j + 4] = f2bf(c);
            }
            int k0 = q * 128 + ch * 8;
            *(u16x8*)&As[r * KDIM + (k0 ^ rx)] = v;
        }
    }
    __syncthreads();   // drains vmcnt(0)+lgkmcnt(0): A visible, B0 arrived

    const int lane = tid & 63;
    const int wid  = tid >> 6;          // 0..7
    const int wr   = wid >> 1;          // 0..3 (M)
    const int wc   = wid & 1;           // 0..1 (N)
    const int l15  = lane & 15;
    const int lq   = lane >> 4;         // 0..3

    f32x4 acc[2][4];
#pragma unroll
    for (int mi = 0; mi < 2; mi++)
#pragma unroll
        for (int ni = 0; ni < 4; ni++) acc[mi][ni] = (f32x4)0.f;

    for (int ci = 0; ci < 64; ++ci) {       // chunk = nt*8 + ks
        const int buf = ci & 1;
        const int nt  = ci >> 3;
        const int ks  = ci & 7;

        // prefetch next chunk into Bs[buf^1] (issue before compute; drained at barrier)
        if (ci + 1 < 64) {
            const int nn = (ci + 1) >> 3;
            const int nk = ((ci + 1) & 7) * BK;
            const unsigned short* bg = Wb + (size_t)(nn * 128) * KDIM + nk + skb;
            __builtin_amdgcn_global_load_lds(
                (const __attribute__((address_space(1))) void*)(bg + (size_t)scol * KDIM),
                (__attribute__((address_space(3))) void*)(&Bs[buf ^ 1][scol * BK + skb]), 16, 0, 0);
            __builtin_amdgcn_global_load_lds(
                (const __attribute__((address_space(1))) void*)(bg + (size_t)(64 + scol) * KDIM),
                (__attribute__((address_space(3))) void*)(&Bs[buf ^ 1][(64 + scol) * BK + skb]), 16, 0, 0);
        }

#pragma unroll
        for (int kk = 0; kk < 2; ++kk) {
            bf16x8 af[2], bf[4];
            const int klo  = ks * BK + kk * 32 + lq * 8;   // within full K (A)
            const int kloB = kk * 32 + lq * 8;             // within chunk (B)
#pragma unroll
            for (int mi = 0; mi < 2; mi++) {
                int row = wr * 32 + mi * 16 + l15;
                af[mi] = *(const bf16x8*)&As[row * KDIM + (klo ^ ((row & 7) << 3))];
            }
#pragma unroll
            for (int ni = 0; ni < 4; ni++) {
                int col = wc * 64 + ni * 16 + l15;
                bf[ni] = *(const bf16x8*)&Bs[buf][col * BK + kloB];
            }
#pragma unroll
            for (int mi = 0; mi < 2; mi++)
#pragma unroll
                for (int ni = 0; ni < 4; ni++)
                    acc[mi][ni] = __builtin_amdgcn_mfma_f32_16x16x32_bf16(
                        af[mi], bf[ni], acc[mi][ni], 0, 0, 0);
        }

        if (ks == 7) {  // per-nt epilogue (regs only, no sync needed before barrier)
#pragma unroll
            for (int ni = 0; ni < 4; ni++) {
                int col = nt * 128 + wc * 64 + ni * 16 + l15;
                float bv = bias[col];
#pragma unroll
                for (int mi = 0; mi < 2; mi++) {
                    int rbase = bt * 128 + wr * 32 + mi * 16 + lq * 4;
#pragma unroll
                    for (int i = 0; i < 4; i++)
                        out[(size_t)(rbase + i) * VDIM + col] = acc[mi][ni][i] + bv;
                    acc[mi][ni] = (f32x4)0.f;
                }
            }
        }
        __syncthreads();   // B dbuf hazard fence (drains prefetch vmcnt)
    }
}

extern "C" void kernel_launch(void* const* d_in, const int* in_sizes, int n_in,
                              void* d_out, int out_size, void* d_ws, size_t ws_size,
                              hipStream_t stream) {
    const float* src  = (const float*)d_in[0];
    const int*   slen = (const int*)d_in[1];
    const float* tgt  = (const float*)d_in[2];
    const int*   tlen = (const int*)d_in[3];
    const float* W    = (const float*)d_in[4];
    const float* bias = (const float*)d_in[5];
    float* out = (float*)d_out;

    unsigned short* Wb = (unsigned short*)d_ws;   // 1,048,576 B

    prep_w<<<256, 256, 0, stream>>>(W, Wb, slen, tlen, out + OUT_MAIN);
    joiner_fused<<<1024, 512, 0, stream>>>(src, tgt, Wb, bias, out);
}